// Round 1
// baseline (3138.075 us; speedup 1.0000x reference)
//
#include <hip/hip_runtime.h>

#define BATCH 1024
#define TT    200
#define EE    100
#define HH    200
#define GG    600   // 3*HH
#define NI    50000

// ---------------- K1: EWi[i][j] = sum_e embed[i][e] * Wi[e][j] ----------------
__global__ __launch_bounds__(640) void ewi_kernel(const float* __restrict__ embed,
                                                  const float* __restrict__ Wi,
                                                  float* __restrict__ EWi) {
    __shared__ __align__(16) float emb_s[32][EE];
    const int i0  = blockIdx.x * 32;
    const int tid = threadIdx.x;
    for (int idx = tid; idx < 32 * EE; idx += 640) {
        int r = idx / EE, e = idx % EE;
        int gr = i0 + r;
        emb_s[r][e] = (gr < NI) ? embed[(size_t)gr * EE + e] : 0.f;
    }
    __syncthreads();
    const int j = tid;
    if (j < GG) {
        float acc[32];
        #pragma unroll
        for (int r = 0; r < 32; ++r) acc[r] = 0.f;
        for (int e = 0; e < EE; ++e) {
            float w = Wi[(size_t)e * GG + j];
            #pragma unroll
            for (int r = 0; r < 32; ++r) acc[r] += emb_s[r][e] * w;
        }
        int rmax = (NI - i0) < 32 ? (NI - i0) : 32;
        for (int r = 0; r < rmax; ++r) EWi[(size_t)(i0 + r) * GG + j] = acc[r];
    }
}

// ---------------- K2: persistent GRU scan, 4 batch rows per block ----------------
// thread i < 200 owns hidden unit i: computes gh_r/gh_z/gh_n columns {i, 200+i, 400+i}
// for 4 batch elements, then combines gates locally. h kept in LDS for all 200 steps.
__global__ __launch_bounds__(256) void scan_kernel(const int* __restrict__ q,
                                                   const float* __restrict__ EWi,
                                                   const float* __restrict__ bi,
                                                   const float* __restrict__ Wh,
                                                   const float* __restrict__ bhn,
                                                   float* __restrict__ h_out) {
    __shared__ __align__(16) float h_s[4][HH];
    const int tid = threadIdx.x;
    const int b0  = blockIdx.x * 4;

    for (int idx = tid; idx < 4 * HH; idx += 256) ((float*)h_s)[idx] = 0.f;
    __syncthreads();

    const int i = tid;
    float bi_r = 0.f, bi_z = 0.f, bi_n = 0.f, bhn_i = 0.f;
    if (i < HH) {
        bi_r  = bi[i];
        bi_z  = bi[HH + i];
        bi_n  = bi[2 * HH + i];
        bhn_i = bhn[i];
    }

    for (int t = 0; t < TT; ++t) {
        float hn_new[4];
        if (i < HH) {
            // --- gather gi rows (issued early; independent of h) ---
            float gr[4], gz[4], gn[4];
            #pragma unroll
            for (int b = 0; b < 4; ++b) {
                int qv = q[(size_t)(b0 + b) * TT + t];
                float r_ = bi_r, z_ = bi_z, n_ = bi_n;
                if (qv != 0) {
                    const float* row = EWi + (size_t)qv * GG;
                    r_ += row[i];
                    z_ += row[HH + i];
                    n_ += row[2 * HH + i];
                }
                gr[b] = r_; gz[b] = z_; gn[b] = n_;
            }
            // --- gh = h @ Wh for this thread's 3 columns, 4 batch rows ---
            float ar[4], az[4], an[4];
            #pragma unroll
            for (int b = 0; b < 4; ++b) { ar[b] = 0.f; az[b] = 0.f; an[b] = 0.f; }
            #pragma unroll 2
            for (int k4 = 0; k4 < HH / 4; ++k4) {
                const float4 f0 = *(const float4*)(&h_s[0][k4 * 4]);
                const float4 f1 = *(const float4*)(&h_s[1][k4 * 4]);
                const float4 f2 = *(const float4*)(&h_s[2][k4 * 4]);
                const float4 f3 = *(const float4*)(&h_s[3][k4 * 4]);
                float hA[4] = {f0.x, f0.y, f0.z, f0.w};
                float hB[4] = {f1.x, f1.y, f1.z, f1.w};
                float hC[4] = {f2.x, f2.y, f2.z, f2.w};
                float hD[4] = {f3.x, f3.y, f3.z, f3.w};
                #pragma unroll
                for (int kk = 0; kk < 4; ++kk) {
                    const float* wp = Wh + (size_t)(k4 * 4 + kk) * GG + i;
                    float wr = wp[0];
                    float wz = wp[HH];
                    float wn = wp[2 * HH];
                    ar[0] += hA[kk] * wr; az[0] += hA[kk] * wz; an[0] += hA[kk] * wn;
                    ar[1] += hB[kk] * wr; az[1] += hB[kk] * wz; an[1] += hB[kk] * wn;
                    ar[2] += hC[kk] * wr; az[2] += hC[kk] * wz; an[2] += hC[kk] * wn;
                    ar[3] += hD[kk] * wr; az[3] += hD[kk] * wz; an[3] += hD[kk] * wn;
                }
            }
            // --- gate combine (flax GRUCell) ---
            #pragma unroll
            for (int b = 0; b < 4; ++b) {
                float rr = 1.f / (1.f + __expf(-(gr[b] + ar[b])));
                float zz = 1.f / (1.f + __expf(-(gz[b] + az[b])));
                float nn = tanhf(gn[b] + rr * (an[b] + bhn_i));
                hn_new[b] = (1.f - zz) * nn + zz * h_s[b][i];
            }
        }
        __syncthreads();
        if (i < HH) {
            h_s[0][i] = hn_new[0];
            h_s[1][i] = hn_new[1];
            h_s[2][i] = hn_new[2];
            h_s[3][i] = hn_new[3];
        }
        __syncthreads();
    }

    for (int idx = tid; idx < 4 * HH; idx += 256)
        h_out[(size_t)b0 * HH + idx] = ((float*)h_s)[idx];
}

// ---------------- K3: out = h_last @ Wo + bo ----------------
// block: 256 threads, tile = 32 batch x 64 cols; thread: 8 batch x 1 col
__global__ __launch_bounds__(256) void out_kernel(const float* __restrict__ h,
                                                  const float* __restrict__ Wo,
                                                  const float* __restrict__ bo,
                                                  float* __restrict__ out) {
    __shared__ __align__(16) float hs[32][HH];
    const int tid   = threadIdx.x;
    const int col0  = blockIdx.x * 64;
    const int brow0 = blockIdx.y * 32;

    for (int idx = tid; idx < 32 * HH; idx += 256) {
        int r = idx / HH, k = idx % HH;
        hs[r][k] = h[(size_t)(brow0 + r) * HH + k];
    }
    __syncthreads();

    const int col = col0 + (tid & 63);
    const int cc  = col < NI ? col : (NI - 1);
    const int bg  = tid >> 6;   // 0..3 -> batch rows bg*8 .. bg*8+7

    float acc[8];
    #pragma unroll
    for (int b = 0; b < 8; ++b) acc[b] = 0.f;

    for (int k4 = 0; k4 < HH / 4; ++k4) {
        float w0 = Wo[(size_t)(k4 * 4 + 0) * NI + cc];
        float w1 = Wo[(size_t)(k4 * 4 + 1) * NI + cc];
        float w2 = Wo[(size_t)(k4 * 4 + 2) * NI + cc];
        float w3 = Wo[(size_t)(k4 * 4 + 3) * NI + cc];
        #pragma unroll
        for (int b = 0; b < 8; ++b) {
            const float4 hv = *(const float4*)(&hs[bg * 8 + b][k4 * 4]);
            acc[b] += hv.x * w0;
            acc[b] += hv.y * w1;
            acc[b] += hv.z * w2;
            acc[b] += hv.w * w3;
        }
    }

    if (col < NI) {
        const float bov = bo[col];
        #pragma unroll
        for (int b = 0; b < 8; ++b) {
            out[(size_t)(brow0 + bg * 8 + b) * NI + col] = acc[b] + bov;
        }
    }
}

extern "C" void kernel_launch(void* const* d_in, const int* in_sizes, int n_in,
                              void* d_out, int out_size, void* d_ws, size_t ws_size,
                              hipStream_t stream) {
    const int*   q     = (const int*)d_in[0];
    const float* embed = (const float*)d_in[1];
    const float* Wi    = (const float*)d_in[2];
    const float* bi    = (const float*)d_in[3];
    const float* Wh    = (const float*)d_in[4];
    const float* bhn   = (const float*)d_in[5];
    const float* Wo    = (const float*)d_in[6];
    const float* bo    = (const float*)d_in[7];
    float* out = (float*)d_out;

    // EWi [50000 x 600] f32 = 120 MB scratch living in d_out (only K3 writes d_out,
    // stream-ordered after the scan). h_last (819 KB) lives in d_ws.
    float* EWi  = out;
    float* hbuf = (float*)d_ws;

    ewi_kernel<<<(NI + 31) / 32, 640, 0, stream>>>(embed, Wi, EWi);
    scan_kernel<<<BATCH / 4, 256, 0, stream>>>(q, EWi, bi, Wh, bhn, hbuf);
    out_kernel<<<dim3((NI + 63) / 64, BATCH / 32), 256, 0, stream>>>(hbuf, Wo, bo, out);
}